// Round 15
// baseline (681.688 us; speedup 1.0000x reference)
//
#include <hip/hip_runtime.h>
#include <hip/hip_fp16.h>
#include <cstdint>
#include <cstddef>
#include <cstring>

#define DIM 128
#define NEG_SLOPE 0.2f

#define EREP 16   // replicas for edge counters
#define NREP 8    // replicas for node counters

typedef _Float16 half8v __attribute__((ext_vector_type(8)));
typedef __attribute__((ext_vector_type(4))) float float4v;

// ---- fp16 helpers ----------------------------------------------------------
__device__ __forceinline__ float2 h2f2(uint u) {
  __half2 h;
  __builtin_memcpy(&h, &u, 4);
  return __half22float2(h);
}
__device__ __forceinline__ uint packh2(float lo, float hi) {
  __half2 h = __floats2half2_rn(lo, hi);
  uint u;
  __builtin_memcpy(&u, &h, 4);
  return u;
}
__device__ __forceinline__ ushort f2h_us(float f) {
  __half h = __float2half_rn(f);
  ushort us;
  __builtin_memcpy(&us, &h, 2);
  return us;
}
__device__ __forceinline__ float lrelu(float x) {
  return x >= 0.0f ? x : NEG_SLOPE * x;
}

// ---------------------------------------------------------------------------
// W pre-swizzle into MFMA B-fragment order, fp16 (once):
// ---------------------------------------------------------------------------
__global__ void wswz_kernel(const float* __restrict__ W, ushort* __restrict__ Wswz)
{
  int i = blockIdx.x * 256 + threadIdx.x;   // 0..16383
  int j = i & 7, lane = (i >> 3) & 63, nt = (i >> 9) & 7, kt = i >> 12;
  int k = kt * 32 + (lane >> 4) * 8 + j;
  int col = nt * 16 + (lane & 15);
  Wswz[i] = f2h_us(W[k * 128 + col]);
}

// ---------------------------------------------------------------------------
// pois -> fp16 (padded rows zeroed)
// ---------------------------------------------------------------------------
__global__ void poish_kernel(const float* __restrict__ pois,
                             uint4* __restrict__ pois_h, int N_, int NP)
{
  int i = blockIdx.x * 256 + threadIdx.x;   // each = 8 fp16 = one uint4
  if (i >= NP * 16) return;
  int row = i >> 4;
  uint4 o;
  if (row < N_) {
    const float* src = pois + (size_t)i * 8;
    float4 f0 = *(const float4*)src;
    float4 f1 = *(const float4*)(src + 4);
    o.x = packh2(f0.x, f0.y); o.y = packh2(f0.z, f0.w);
    o.z = packh2(f1.x, f1.y); o.w = packh2(f1.z, f1.w);
  } else { o.x = o.y = o.z = o.w = 0; }
  pois_h[i] = o;
}

// ---------------------------------------------------------------------------
// PREP FUSED: blockIdx-partitioned roles. Hist needs FULL wave parallelism
// (R14 measurement: fabric RMW rate scales with issuing-wave count — halving
// waves doubled hist time), so hist gets 1 pair/thread = cdiv(NNZ,512) blocks
// exactly like the standalone kernel. gemm L0 + se blocks queue behind and
// fill CU slots as hist blocks retire.
// ---------------------------------------------------------------------------
__global__ __launch_bounds__(256) void prep_fused_kernel(
    // hist
    const int* __restrict__ node_idx, const int* __restrict__ edge_idx,
    int* __restrict__ ncnt_r, int* __restrict__ ecnt_r,
    int* __restrict__ r_n, int* __restrict__ r_e,
    int nnz, int M_, int N_, int histBlocks,
    // gemm L0
    const ushort* __restrict__ Xb, const ushort* __restrict__ Wswz,
    const float* __restrict__ att, ushort* __restrict__ Yb,
    float* __restrict__ s_n, int rowsN, int gemmBlocks,
    // se
    const float* __restrict__ traj, const float* __restrict__ W,
    const float* __restrict__ hw,
    float* __restrict__ s_e, float2* __restrict__ se_hw)
{
  __shared__ ushort st[64 * 128];
  int b = blockIdx.x;
  int tid = threadIdx.x;

  if (b < histBlocks) {
    // ---- hist branch: 1 pair/thread (full wave parallelism) ----
    int t = b * 256 + tid;
    int j = t * 2;
    if (j >= nnz) return;
    int* ec = ecnt_r + (size_t)(t & (EREP - 1)) * M_;
    int* nc = ncnt_r + (size_t)(t & (NREP - 1)) * N_;
    if (j + 2 <= nnz) {
      int2 e = *(const int2*)&edge_idx[j];
      int2 n = *(const int2*)&node_idx[j];
      int a0 = atomicAdd(&ec[e.x], 1);
      int a1 = atomicAdd(&ec[e.y], 1);
      int b0 = atomicAdd(&nc[n.x], 1);
      int b1 = atomicAdd(&nc[n.y], 1);
      *(int2*)&r_e[j] = make_int2(a0, a1);
      *(int2*)&r_n[j] = make_int2(b0, b1);
    } else {
      r_e[j] = atomicAdd(&ec[edge_idx[j]], 1);
      r_n[j] = atomicAdd(&nc[node_idx[j]], 1);
    }
    return;
  }

  if (b < histBlocks + gemmBlocks) {
    // ---- gemm L0 branch ----
    int bb = b - histBlocks;
    int w = tid >> 6, lane = tid & 63;
    int q = lane >> 4, c = lane & 15;
    int r0b = bb * 64;
    int r0 = r0b + w * 16;
    float4v acc[8];
#pragma unroll
    for (int nt = 0; nt < 8; ++nt) acc[nt] = (float4v){0.f, 0.f, 0.f, 0.f};
    const ushort* arow = Xb + (size_t)(r0 + c) * DIM + q * 8;
#pragma unroll
    for (int kt = 0; kt < 4; ++kt) {
      half8v a = *(const half8v*)(arow + kt * 32);
#pragma unroll
      for (int nt = 0; nt < 8; ++nt) {
        half8v bfr = *(const half8v*)(Wswz + ((((kt << 3) + nt) << 9) + (lane << 3)));
        acc[nt] = __builtin_amdgcn_mfma_f32_16x16x32_f16(a, bfr, acc[nt], 0, 0, 0);
      }
    }
    float av[8];
#pragma unroll
    for (int nt = 0; nt < 8; ++nt) av[nt] = att[nt * 16 + c];
    float p0 = 0, p1 = 0, p2 = 0, p3 = 0;
#pragma unroll
    for (int nt = 0; nt < 8; ++nt) {
      p0 = fmaf(acc[nt][0], av[nt], p0);
      p1 = fmaf(acc[nt][1], av[nt], p1);
      p2 = fmaf(acc[nt][2], av[nt], p2);
      p3 = fmaf(acc[nt][3], av[nt], p3);
    }
#pragma unroll
    for (int m = 8; m >= 1; m >>= 1) {
      p0 += __shfl_xor(p0, m, 64);
      p1 += __shfl_xor(p1, m, 64);
      p2 += __shfl_xor(p2, m, 64);
      p3 += __shfl_xor(p3, m, 64);
    }
    if (c == 0) {
      int rb = r0 + q * 4;
      if (rb + 0 < rowsN) s_n[rb + 0] = p0;
      if (rb + 1 < rowsN) s_n[rb + 1] = p1;
      if (rb + 2 < rowsN) s_n[rb + 2] = p2;
      if (rb + 3 < rowsN) s_n[rb + 3] = p3;
    }
    ushort* sw = st + w * 2048;
#pragma unroll
    for (int nt = 0; nt < 8; ++nt) {
      sw[(q * 4 + 0) * 128 + nt * 16 + c] = f2h_us(acc[nt][0]);
      sw[(q * 4 + 1) * 128 + nt * 16 + c] = f2h_us(acc[nt][1]);
      sw[(q * 4 + 2) * 128 + nt * 16 + c] = f2h_us(acc[nt][2]);
      sw[(q * 4 + 3) * 128 + nt * 16 + c] = f2h_us(acc[nt][3]);
    }
    __syncthreads();
#pragma unroll
    for (int it = 0; it < 4; ++it) {
      int idx = tid + it * 256;
      int row = idx >> 4, seg = idx & 15;
      *(uint4*)(Yb + (size_t)(r0b + row) * DIM + seg * 8) =
          *(const uint4*)&st[row * 128 + seg * 8];
    }
    return;
  }

  // ---- se branch ----
  {
    float* wv = (float*)st;
    if (tid < 128) {
      const float* wr = W + (size_t)tid * 128;
      float acc = 0.0f;
#pragma unroll 4
      for (int k = 0; k < 128; ++k) acc = fmaf(wr[k], att[DIM + k], acc);
      wv[tid] = acc;
    }
    __syncthreads();
    int e = (b - histBlocks - gemmBlocks) * 4 + (tid >> 6);
    int lane = tid & 63;
    if (e >= M_) return;
    const float* row = traj + (size_t)e * DIM;
    float v = row[lane] * wv[lane] + row[lane + 64] * wv[lane + 64];
#pragma unroll
    for (int d = 32; d > 0; d >>= 1) v += __shfl_down(v, d, 64);
    if (lane == 0) {
      s_e[e] = v;
      float2 g; g.x = v; g.y = hw[e];
      se_hw[e] = g;
    }
  }
}

// ---------------------------------------------------------------------------
// MFMA GEMM (fp16), standalone for layers 1,2.
// ---------------------------------------------------------------------------
__global__ __launch_bounds__(256) void gemm_mfma_kernel(
    const ushort* __restrict__ Xb, const ushort* __restrict__ Wswz,
    const float* __restrict__ att, ushort* __restrict__ Yb,
    float* __restrict__ s_n, int rowsN)
{
  __shared__ ushort st[64 * 128];
  int tid = threadIdx.x;
  int w = tid >> 6, lane = tid & 63;
  int q = lane >> 4, c = lane & 15;
  int r0b = blockIdx.x * 64;
  int r0 = r0b + w * 16;
  float4v acc[8];
#pragma unroll
  for (int nt = 0; nt < 8; ++nt) acc[nt] = (float4v){0.f, 0.f, 0.f, 0.f};
  const ushort* arow = Xb + (size_t)(r0 + c) * DIM + q * 8;
#pragma unroll
  for (int kt = 0; kt < 4; ++kt) {
    half8v a = *(const half8v*)(arow + kt * 32);
#pragma unroll
    for (int nt = 0; nt < 8; ++nt) {
      half8v b = *(const half8v*)(Wswz + ((((kt << 3) + nt) << 9) + (lane << 3)));
      acc[nt] = __builtin_amdgcn_mfma_f32_16x16x32_f16(a, b, acc[nt], 0, 0, 0);
    }
  }
  float av[8];
#pragma unroll
  for (int nt = 0; nt < 8; ++nt) av[nt] = att[nt * 16 + c];
  float p0 = 0, p1 = 0, p2 = 0, p3 = 0;
#pragma unroll
  for (int nt = 0; nt < 8; ++nt) {
    p0 = fmaf(acc[nt][0], av[nt], p0);
    p1 = fmaf(acc[nt][1], av[nt], p1);
    p2 = fmaf(acc[nt][2], av[nt], p2);
    p3 = fmaf(acc[nt][3], av[nt], p3);
  }
#pragma unroll
  for (int m = 8; m >= 1; m >>= 1) {
    p0 += __shfl_xor(p0, m, 64);
    p1 += __shfl_xor(p1, m, 64);
    p2 += __shfl_xor(p2, m, 64);
    p3 += __shfl_xor(p3, m, 64);
  }
  if (c == 0) {
    int rb = r0 + q * 4;
    if (rb + 0 < rowsN) s_n[rb + 0] = p0;
    if (rb + 1 < rowsN) s_n[rb + 1] = p1;
    if (rb + 2 < rowsN) s_n[rb + 2] = p2;
    if (rb + 3 < rowsN) s_n[rb + 3] = p3;
  }
  ushort* sw = st + w * 2048;
#pragma unroll
  for (int nt = 0; nt < 8; ++nt) {
    sw[(q * 4 + 0) * 128 + nt * 16 + c] = f2h_us(acc[nt][0]);
    sw[(q * 4 + 1) * 128 + nt * 16 + c] = f2h_us(acc[nt][1]);
    sw[(q * 4 + 2) * 128 + nt * 16 + c] = f2h_us(acc[nt][2]);
    sw[(q * 4 + 3) * 128 + nt * 16 + c] = f2h_us(acc[nt][3]);
  }
  __syncthreads();
#pragma unroll
  for (int it = 0; it < 4; ++it) {
    int idx = tid + it * 256;
    int row = idx >> 4, seg = idx & 15;
    *(uint4*)(Yb + (size_t)(r0b + row) * DIM + seg * 8) =
        *(const uint4*)&st[row * 128 + seg * 8];
  }
}

// ---------------------------------------------------------------------------
// Per-bin exclusive prefix across replicas (in place) + total into cnt.
// ---------------------------------------------------------------------------
__global__ void repsum_kernel(int* __restrict__ cnt_r, int* __restrict__ cnt,
                              int nbins, int reps)
{
  int b = blockIdx.x * blockDim.x + threadIdx.x;
  if (b >= nbins) return;
  int s = 0;
  for (int r = 0; r < reps; ++r) {
    size_t o = (size_t)r * nbins + b;
    int v = cnt_r[o];
    cnt_r[o] = s;
    s += v;
  }
  cnt[b] = s;
}

// ---------------------------------------------------------------------------
// Two-level exclusive scan
// ---------------------------------------------------------------------------
__global__ __launch_bounds__(1024) void scan_block_kernel(
    const int* __restrict__ cnt, int* __restrict__ off,
    int* __restrict__ partials, int nbins)
{
  __shared__ int ws[16];
  int tid = threadIdx.x, lane = tid & 63, wid = tid >> 6;
  int base = blockIdx.x * 4096 + tid * 4;
  int x0 = base + 0 < nbins ? cnt[base + 0] : 0;
  int x1 = base + 1 < nbins ? cnt[base + 1] : 0;
  int x2 = base + 2 < nbins ? cnt[base + 2] : 0;
  int x3 = base + 3 < nbins ? cnt[base + 3] : 0;
  int t = x0 + x1 + x2 + x3;
  int v = t;
#pragma unroll
  for (int d = 1; d < 64; d <<= 1) {
    int y = __shfl_up(v, d, 64);
    if (lane >= d) v += y;
  }
  if (lane == 63) ws[wid] = v;
  __syncthreads();
  if (tid < 16) {
    int s = ws[tid];
#pragma unroll
    for (int d = 1; d < 16; d <<= 1) {
      int y = __shfl_up(s, d, 16);
      if (tid >= d) s += y;
    }
    ws[tid] = s;
  }
  __syncthreads();
  int pre = (wid > 0 ? ws[wid - 1] : 0) + (v - t);
  if (base + 0 < nbins) off[base + 0] = pre;
  if (base + 1 < nbins) off[base + 1] = pre + x0;
  if (base + 2 < nbins) off[base + 2] = pre + x0 + x1;
  if (base + 3 < nbins) off[base + 3] = pre + x0 + x1 + x2;
  if (tid == 0) partials[blockIdx.x] = ws[15];
}

__global__ __launch_bounds__(64) void scan_partials_kernel(
    int* __restrict__ partials, int nb)
{
  int lane = threadIdx.x;
  int t = lane < nb ? partials[lane] : 0;
  int v = t;
#pragma unroll
  for (int d = 1; d < 64; d <<= 1) {
    int y = __shfl_up(v, d, 64);
    if (lane >= d) v += y;
  }
  if (lane < nb) partials[lane] = v - t;
  if (lane == 63) partials[nb] = v;
}

// add block partials into off AND fold the final offsets into the replica
// prefixes so scatter needs only ONE gather: pos = pre[rep][bin] + local_rank.
__global__ void add_off_combine_kernel(int* __restrict__ off,
                                       const int* __restrict__ partials,
                                       int* __restrict__ pre,
                                       int nbins, int nb, int reps)
{
  int i = blockIdx.x * blockDim.x + threadIdx.x;
  if (i < nbins) {
    int o = off[i] + partials[i >> 12];
    off[i] = o;
    for (int r = 0; r < reps; ++r) pre[(size_t)r * nbins + i] += o;
  }
  if (i == 0) off[nbins] = partials[nb];
}

// ---------------------------------------------------------------------------
// SPLIT atomic-free CSR scatters (replica-aware combined offsets)
// ---------------------------------------------------------------------------
__global__ void scatter_edge_kernel(const int* __restrict__ node_idx,
                                    const int* __restrict__ edge_idx,
                                    const int* __restrict__ r_e,
                                    const int* __restrict__ pre_e,
                                    int* __restrict__ nd_e, int nnz, int M_)
{
  int j = (blockIdx.x * blockDim.x + threadIdx.x) * 4;
  if (j >= nnz) return;
  if (j + 4 <= nnz) {
    const int* p0 = pre_e + (size_t)((j >> 1) & (EREP - 1)) * M_;
    const int* p1 = pre_e + (size_t)(((j >> 1) + 1) & (EREP - 1)) * M_;
    int4 e = *(const int4*)&edge_idx[j];
    int4 n = *(const int4*)&node_idx[j];
    int4 re = *(const int4*)&r_e[j];
    nd_e[p0[e.x] + re.x] = n.x;
    nd_e[p0[e.y] + re.y] = n.y;
    nd_e[p1[e.z] + re.z] = n.z;
    nd_e[p1[e.w] + re.w] = n.w;
  } else {
    for (int k = j; k < nnz; ++k) {
      const int* pp = pre_e + (size_t)((k >> 1) & (EREP - 1)) * M_;
      nd_e[pp[edge_idx[k]] + r_e[k]] = node_idx[k];
    }
  }
}

__global__ void scatter_node_kernel(const int* __restrict__ node_idx,
                                    const int* __restrict__ edge_idx,
                                    const int* __restrict__ r_n,
                                    const int* __restrict__ pre_n,
                                    int* __restrict__ eidx_n, int nnz, int N_)
{
  int j = (blockIdx.x * blockDim.x + threadIdx.x) * 4;
  if (j >= nnz) return;
  if (j + 4 <= nnz) {
    const int* p0 = pre_n + (size_t)((j >> 1) & (NREP - 1)) * N_;
    const int* p1 = pre_n + (size_t)(((j >> 1) + 1) & (NREP - 1)) * N_;
    int4 e = *(const int4*)&edge_idx[j];
    int4 n = *(const int4*)&node_idx[j];
    int4 rn = *(const int4*)&r_n[j];
    eidx_n[p0[n.x] + rn.x] = e.x;
    eidx_n[p0[n.y] + rn.y] = e.y;
    eidx_n[p1[n.z] + rn.z] = e.z;
    eidx_n[p1[n.w] + rn.w] = e.w;
  } else {
    for (int k = j; k < nnz; ++k) {
      const int* pp = pre_n + (size_t)((k >> 1) & (NREP - 1)) * N_;
      eidx_n[pp[node_idx[k]] + r_n[k]] = edge_idx[k];
    }
  }
}

// ---------------------------------------------------------------------------
// Per-node softmax stats + weighted degree
// ---------------------------------------------------------------------------
__global__ void softstat_kernel(const int* __restrict__ noff,
                                const int* __restrict__ eidx_n,
                                const float* __restrict__ s_n,
                                const float2* __restrict__ se_hw,
                                float2* __restrict__ ns2,
                                float* __restrict__ Dinv, int N_)
{
  int n = blockIdx.x * blockDim.x + threadIdx.x;
  if (n >= N_) return;
  int s = noff[n], e1 = noff[n + 1];
  float sn = s_n[n];
  float m = -INFINITY, den = 0.0f, d = 0.0f;
  int t = s;
  for (; t + 4 <= e1; t += 4) {
    int i0 = eidx_n[t], i1 = eidx_n[t + 1], i2 = eidx_n[t + 2], i3 = eidx_n[t + 3];
    float2 g0 = se_hw[i0], g1 = se_hw[i1], g2 = se_hw[i2], g3 = se_hw[i3];
    float l0 = lrelu(sn + g0.x), l1 = lrelu(sn + g1.x);
    float l2 = lrelu(sn + g2.x), l3 = lrelu(sn + g3.x);
    float mm = fmaxf(fmaxf(fmaxf(l0, l1), fmaxf(l2, l3)), m);
    den = den * __expf(m - mm) + __expf(l0 - mm) + __expf(l1 - mm)
        + __expf(l2 - mm) + __expf(l3 - mm);
    m = mm;
    d += g0.y + g1.y + g2.y + g3.y;
  }
  for (; t < e1; ++t) {
    float2 g = se_hw[eidx_n[t]];
    float l = lrelu(sn + g.x);
    float mm = fmaxf(l, m);
    den = den * __expf(m - mm) + __expf(l - mm);
    m = mm;
    d += g.y;
  }
  if (s == e1) m = 0.0f;
  float2 r;
  r.x = sn;
  r.y = m + __logf(den + 1e-16f);
  ns2[n] = r;
  Dinv[n] = d > 0.0f ? 1.0f / d : 0.0f;
}

// ---------------------------------------------------------------------------
// msg1 WIDE: wave per edge; lane = (row-group r = lane>>4, col-group c = lane&15).
// One uint4 gather instruction covers 4 incidence rows (64 lanes x 16B = 1KB).
// ---------------------------------------------------------------------------
__global__ __launch_bounds__(256) void msg1_kernel(
    const int* __restrict__ eoff, const int* __restrict__ nd_e,
    const float2* __restrict__ ns2, const float* __restrict__ s_e,
    const uint4* __restrict__ xt16, uint4* __restrict__ eo16, int M_)
{
  int e = blockIdx.x * 4 + (threadIdx.x >> 6);
  int lane = threadIdx.x & 63;
  int r = lane >> 4, c = lane & 15;
  if (e >= M_) return;
  int s = eoff[e], t1 = eoff[e + 1];
  int len = t1 - s;
  float binv = len > 0 ? 1.0f / (float)len : 0.0f;
  float se = s_e[e];
  float acc[8];
#pragma unroll
  for (int j = 0; j < 8; ++j) acc[j] = 0.0f;
  for (int t = s; t < t1; t += 8) {
#pragma unroll
    for (int h = 0; h < 2; ++h) {
      int tb = t + h * 4;
      if (tb < t1) {
        int ti = tb + r;
        int tc = ti < t1 ? ti : t1 - 1;
        float valid = ti < t1 ? 1.0f : 0.0f;
        int nd = nd_e[tc];
        float2 q = ns2[nd];
        float coef = valid * __expf(lrelu(q.x + se) - q.y);
        uint4 g = xt16[(size_t)nd * 16 + c];
        float2 f0 = h2f2(g.x), f1 = h2f2(g.y), f2 = h2f2(g.z), f3 = h2f2(g.w);
        acc[0] = fmaf(coef, f0.x, acc[0]);
        acc[1] = fmaf(coef, f0.y, acc[1]);
        acc[2] = fmaf(coef, f1.x, acc[2]);
        acc[3] = fmaf(coef, f1.y, acc[3]);
        acc[4] = fmaf(coef, f2.x, acc[4]);
        acc[5] = fmaf(coef, f2.y, acc[5]);
        acc[6] = fmaf(coef, f3.x, acc[6]);
        acc[7] = fmaf(coef, f3.y, acc[7]);
      }
    }
  }
#pragma unroll
  for (int j = 0; j < 8; ++j) {
    acc[j] += __shfl_xor(acc[j], 16, 64);
    acc[j] += __shfl_xor(acc[j], 32, 64);
  }
  if (r == 0) {
    uint4 o;
    o.x = packh2(acc[0] * binv, acc[1] * binv);
    o.y = packh2(acc[2] * binv, acc[3] * binv);
    o.z = packh2(acc[4] * binv, acc[5] * binv);
    o.w = packh2(acc[6] * binv, acc[7] * binv);
    eo16[(size_t)e * 16 + c] = o;
  }
}

// ---------------------------------------------------------------------------
// msg2 WIDE: fp16 residual chain (cin always fp16) + lazy stack-sum epilogue.
//  mode 0/1: out = cur_h (fp16)
//  mode 2:   dout = 0.25*(h(x1h) + h(x2h) + cin + cx)
// ---------------------------------------------------------------------------
__global__ __launch_bounds__(256) void msg2_kernel(
    const int* __restrict__ noff, const int* __restrict__ eidx_n,
    const float2* __restrict__ ns2, const float* __restrict__ Dinv,
    const float* __restrict__ s_e, const uint4* __restrict__ eo16,
    const float* __restrict__ bias,
    const uint4* __restrict__ cin_h16,
    const uint4* __restrict__ x1h16, const uint4* __restrict__ x2h16,
    uint4* __restrict__ couth16, float* __restrict__ dout,
    int mode, int N_)
{
  int n = blockIdx.x * 4 + (threadIdx.x >> 6);
  int lane = threadIdx.x & 63;
  int r = lane >> 4, c = lane & 15;
  if (n >= N_) return;
  int s = noff[n], t1 = noff[n + 1];
  float2 nsv = ns2[n];
  float sn = nsv.x, lz = nsv.y;
  float acc[8];
#pragma unroll
  for (int j = 0; j < 8; ++j) acc[j] = 0.0f;
  for (int t = s; t < t1; t += 8) {
#pragma unroll
    for (int h = 0; h < 2; ++h) {
      int tb = t + h * 4;
      if (tb < t1) {
        int ti = tb + r;
        int tc = ti < t1 ? ti : t1 - 1;
        float valid = ti < t1 ? 1.0f : 0.0f;
        int ed = eidx_n[tc];
        float xs = s_e[ed];
        float coef = valid * __expf(lrelu(sn + xs) - lz);
        uint4 g = eo16[(size_t)ed * 16 + c];
        float2 f0 = h2f2(g.x), f1 = h2f2(g.y), f2 = h2f2(g.z), f3 = h2f2(g.w);
        acc[0] = fmaf(coef, f0.x, acc[0]);
        acc[1] = fmaf(coef, f0.y, acc[1]);
        acc[2] = fmaf(coef, f1.x, acc[2]);
        acc[3] = fmaf(coef, f1.y, acc[3]);
        acc[4] = fmaf(coef, f2.x, acc[4]);
        acc[5] = fmaf(coef, f2.y, acc[5]);
        acc[6] = fmaf(coef, f3.x, acc[6]);
        acc[7] = fmaf(coef, f3.y, acc[7]);
      }
    }
  }
#pragma unroll
  for (int j = 0; j < 8; ++j) {
    acc[j] += __shfl_xor(acc[j], 16, 64);
    acc[j] += __shfl_xor(acc[j], 32, 64);
  }
  if (r != 0) return;
  float sc = Dinv[n];
  uint4 ch = cin_h16[(size_t)n * 16 + c];
  float2 p0 = h2f2(ch.x), p1 = h2f2(ch.y), p2 = h2f2(ch.z), p3 = h2f2(ch.w);
  float cin[8] = {p0.x, p0.y, p1.x, p1.y, p2.x, p2.y, p3.x, p3.y};
  const float4* bf = (const float4*)bias;
  float4 ba = bf[c * 2], bb = bf[c * 2 + 1];
  float bs[8] = {ba.x, ba.y, ba.z, ba.w, bb.x, bb.y, bb.z, bb.w};
  float cx[8];
#pragma unroll
  for (int j = 0; j < 8; ++j) cx[j] = cin[j] + acc[j] * sc + bs[j];
  if (mode == 2) {
    uint4 x1 = x1h16[(size_t)n * 16 + c];
    float2 z0 = h2f2(x1.x), z1 = h2f2(x1.y), z2 = h2f2(x1.z), z3 = h2f2(x1.w);
    float x1v[8] = {z0.x, z0.y, z1.x, z1.y, z2.x, z2.y, z3.x, z3.y};
    uint4 x2 = x2h16[(size_t)n * 16 + c];
    float2 y0 = h2f2(x2.x), y1 = h2f2(x2.y), y2 = h2f2(x2.z), y3 = h2f2(x2.w);
    float x2v[8] = {y0.x, y0.y, y1.x, y1.y, y2.x, y2.y, y3.x, y3.y};
    float4 o0, o1;
    o0.x = (x1v[0] + x2v[0] + cin[0] + cx[0]) * 0.25f;
    o0.y = (x1v[1] + x2v[1] + cin[1] + cx[1]) * 0.25f;
    o0.z = (x1v[2] + x2v[2] + cin[2] + cx[2]) * 0.25f;
    o0.w = (x1v[3] + x2v[3] + cin[3] + cx[3]) * 0.25f;
    o1.x = (x1v[4] + x2v[4] + cin[4] + cx[4]) * 0.25f;
    o1.y = (x1v[5] + x2v[5] + cin[5] + cx[5]) * 0.25f;
    o1.z = (x1v[6] + x2v[6] + cin[6] + cx[6]) * 0.25f;
    o1.w = (x1v[7] + x2v[7] + cin[7] + cx[7]) * 0.25f;
    float4* dp = (float4*)(dout + (size_t)n * DIM);
    dp[c * 2] = o0;
    dp[c * 2 + 1] = o1;
  } else {
    uint4 o;
    o.x = packh2(cx[0], cx[1]);
    o.y = packh2(cx[2], cx[3]);
    o.z = packh2(cx[4], cx[5]);
    o.w = packh2(cx[6], cx[7]);
    couth16[(size_t)n * 16 + c] = o;
  }
}

// ---------------------------------------------------------------------------
static inline int cdiv(int a, int b) { return (a + b - 1) / b; }

extern "C" void kernel_launch(void* const* d_in, const int* in_sizes, int n_in,
                              void* d_out, int out_size, void* d_ws, size_t ws_size,
                              hipStream_t stream)
{
  const float* pois = (const float*)d_in[0];
  const float* traj = (const float*)d_in[1];
  const float* hw   = (const float*)d_in[2];
  const int* node_idx = (const int*)d_in[3];
  const int* edge_idx = (const int*)d_in[4];
  const float* W    = (const float*)d_in[5];
  const float* att  = (const float*)d_in[6];
  const float* bias = (const float*)d_in[7];
  float* dout = (float*)d_out;

  const int N   = in_sizes[0] / DIM;
  const int M   = in_sizes[2];
  const int NNZ = in_sizes[3];
  const int NP  = (N + 63) & ~63;   // row-padded for 64-row MFMA tiles

  char* p = (char*)d_ws;
  auto alloc = [&](size_t bytes) -> void* {
    void* r = (void*)p;
    p += (bytes + 255) & ~(size_t)255;
    return r;
  };
  ushort* xt_h    = (ushort*)alloc((size_t)NP * DIM * 2);
  ushort* pois_h  = (ushort*)alloc((size_t)NP * DIM * 2);
  uint*   cura_h  = (uint*)alloc((size_t)NP * 64 * 4);   // cur1 fp16
  uint*   curb_h  = (uint*)alloc((size_t)NP * 64 * 4);   // cur2 fp16
  ushort* W_swz   = (ushort*)alloc(16384 * 2);
  uint*   eo_h  = (uint*)alloc((size_t)M * (DIM / 2) * 4);
  float2* ns2   = (float2*)alloc((size_t)N * 8);
  float*  s_e  = (float*)alloc((size_t)M * 4);
  float2* se_hw = (float2*)alloc((size_t)M * 8);
  float*  s_n  = (float*)alloc((size_t)N * 4);
  float*  Dinv = (float*)alloc((size_t)N * 4);
  int* ecnt   = (int*)alloc((size_t)M * 4);
  int* ncnt   = (int*)alloc((size_t)N * 4);
  int* ecnt_r = (int*)alloc((size_t)EREP * M * 4);   // replicated counters / prefixes
  int* ncnt_r = (int*)alloc((size_t)NREP * N * 4);
  int* eoff = (int*)alloc((size_t)(M + 1) * 4);
  int* noff = (int*)alloc((size_t)(N + 1) * 4);
  int* r_e  = (int*)alloc((size_t)NNZ * 4);
  int* r_n  = (int*)alloc((size_t)NNZ * 4);
  int* nd_e   = (int*)alloc((size_t)NNZ * 4);
  int* eidx_n = (int*)alloc((size_t)NNZ * 4);
  int* part_e = (int*)alloc(65 * 4);
  int* part_n = (int*)alloc(65 * 4);
  (void)ws_size;

  const int nbE = cdiv(M, 4096), nbN = cdiv(N, 4096);
  const int histBlocks = cdiv(NNZ, 512);   // 1 pair/thread: full wave parallelism
  const int gemmBlocks = NP / 64;
  const int seBlocks = cdiv(M, 4);

  // ---- prep: fp16 mirrors + W swizzle (needed by fused gemm L0) ----
  hipMemsetAsync(ecnt_r, 0, (size_t)EREP * M * 4, stream);
  hipMemsetAsync(ncnt_r, 0, (size_t)NREP * N * 4, stream);
  wswz_kernel<<<64, 256, 0, stream>>>(W, W_swz);
  poish_kernel<<<cdiv(NP * 16, 256), 256, 0, stream>>>(pois, (uint4*)pois_h, N, NP);

  // ---- fused: hist (full parallelism) + gemm L0 + se tail-fill ----
  prep_fused_kernel<<<histBlocks + gemmBlocks + seBlocks, 256, 0, stream>>>(
      node_idx, edge_idx, ncnt_r, ecnt_r, r_n, r_e, NNZ, M, N, histBlocks,
      pois_h, W_swz, att, xt_h, s_n, N, gemmBlocks,
      traj, W, hw, s_e, se_hw);

  // ---- CSR finalize ----
  repsum_kernel<<<cdiv(M, 256), 256, 0, stream>>>(ecnt_r, ecnt, M, EREP);
  repsum_kernel<<<cdiv(N, 256), 256, 0, stream>>>(ncnt_r, ncnt, N, NREP);
  scan_block_kernel<<<nbE, 1024, 0, stream>>>(ecnt, eoff, part_e, M);
  scan_block_kernel<<<nbN, 1024, 0, stream>>>(ncnt, noff, part_n, N);
  scan_partials_kernel<<<1, 64, 0, stream>>>(part_e, nbE);
  scan_partials_kernel<<<1, 64, 0, stream>>>(part_n, nbN);
  add_off_combine_kernel<<<cdiv(M, 256), 256, 0, stream>>>(eoff, part_e, ecnt_r, M, nbE, EREP);
  add_off_combine_kernel<<<cdiv(N, 256), 256, 0, stream>>>(noff, part_n, ncnt_r, N, nbN, NREP);
  scatter_edge_kernel<<<cdiv(NNZ, 1024), 256, 0, stream>>>(node_idx, edge_idx, r_e, ecnt_r, nd_e, NNZ, M);
  scatter_node_kernel<<<cdiv(NNZ, 1024), 256, 0, stream>>>(node_idx, edge_idx, r_n, ncnt_r, eidx_n, NNZ, N);

  // ---- layers ----
  // L0: (gemm done in fused) msg2: cin=pois_h -> cura_h
  // L1: gemm(cura_h); msg2: cin=cura_h -> curb_h
  // L2: gemm(curb_h); msg2 mode2: cin=curb_h, x1=pois_h, x2=cura_h -> dout
  for (int layer = 0; layer < 3; ++layer) {
    if (layer > 0) {
      const ushort* gin = (layer == 1) ? (const ushort*)cura_h
                                       : (const ushort*)curb_h;
      gemm_mfma_kernel<<<NP / 64, 256, 0, stream>>>(gin, W_swz, att, xt_h, s_n, N);
    }
    softstat_kernel<<<cdiv(N, 256), 256, 0, stream>>>(noff, eidx_n, s_n, se_hw, ns2, Dinv, N);
    msg1_kernel<<<cdiv(M, 4), 256, 0, stream>>>(eoff, nd_e, ns2, s_e,
                                                (const uint4*)xt_h, (uint4*)eo_h, M);
    const uint* cin_h = (layer == 0) ? (const uint*)pois_h
                       : (layer == 1) ? cura_h : curb_h;
    uint* couth = (layer == 0) ? cura_h : curb_h;
    msg2_kernel<<<cdiv(N, 4), 256, 0, stream>>>(noff, eidx_n, ns2, Dinv, s_e,
                                                (const uint4*)eo_h, bias,
                                                (const uint4*)cin_h,
                                                (const uint4*)pois_h,
                                                (const uint4*)cura_h,
                                                (uint4*)couth, dout, layer, N);
  }
}

// Round 19
// 665.084 us; speedup vs baseline: 1.0250x; 1.0250x over previous
//
#include <hip/hip_runtime.h>
#include <hip/hip_fp16.h>
#include <cstdint>
#include <cstddef>
#include <cstring>

#define DIM 128
#define NEG_SLOPE 0.2f

typedef _Float16 half8v __attribute__((ext_vector_type(8)));
typedef __attribute__((ext_vector_type(4))) float float4v;

// ---- fp16 helpers ----------------------------------------------------------
__device__ __forceinline__ float2 h2f2(uint u) {
  __half2 h;
  __builtin_memcpy(&h, &u, 4);
  return __half22float2(h);
}
__device__ __forceinline__ uint packh2(float lo, float hi) {
  __half2 h = __floats2half2_rn(lo, hi);
  uint u;
  __builtin_memcpy(&u, &h, 4);
  return u;
}
__device__ __forceinline__ ushort f2h_us(float f) {
  __half h = __float2half_rn(f);
  ushort us;
  __builtin_memcpy(&us, &h, 2);
  return us;
}
__device__ __forceinline__ float lrelu(float x) {
  return x >= 0.0f ? x : NEG_SLOPE * x;
}

// ---------------------------------------------------------------------------
// W pre-swizzle into MFMA B-fragment order, fp16 (once):
// ---------------------------------------------------------------------------
__global__ void wswz_kernel(const float* __restrict__ W, ushort* __restrict__ Wswz)
{
  int i = blockIdx.x * 256 + threadIdx.x;   // 0..16383
  int j = i & 7, lane = (i >> 3) & 63, nt = (i >> 9) & 7, kt = i >> 12;
  int k = kt * 32 + (lane >> 4) * 8 + j;
  int col = nt * 16 + (lane & 15);
  Wswz[i] = f2h_us(W[k * 128 + col]);
}

// ---------------------------------------------------------------------------
// pois -> fp16 (padded rows zeroed)
// ---------------------------------------------------------------------------
__global__ void poish_kernel(const float* __restrict__ pois,
                             uint4* __restrict__ pois_h, int N_, int NP)
{
  int i = blockIdx.x * 256 + threadIdx.x;   // each = 8 fp16 = one uint4
  if (i >= NP * 16) return;
  int row = i >> 4;
  uint4 o;
  if (row < N_) {
    const float* src = pois + (size_t)i * 8;
    float4 f0 = *(const float4*)src;
    float4 f1 = *(const float4*)(src + 4);
    o.x = packh2(f0.x, f0.y); o.y = packh2(f0.z, f0.w);
    o.z = packh2(f1.x, f1.y); o.w = packh2(f1.z, f1.w);
  } else { o.x = o.y = o.z = o.w = 0; }
  pois_h[i] = o;
}

// ---------------------------------------------------------------------------
// HIST+SE FUSED, SMALL FOOTPRINT (512 B LDS, ~24 VGPR): hist blocks keep
// near-standalone occupancy (R15: the 56-VGPR/16KB-LDS gemm branch had cut
// hist occupancy 56%->39% and stretched it 80->~120 us). se blocks tail-fill.
//  blocks [0, histBlocks)            : hist, 1 pair/thread, single counters
//  blocks [histBlocks, +seBlocks)    : se
// ---------------------------------------------------------------------------
__global__ __launch_bounds__(256) void hist_se_fused_kernel(
    // hist (single counter array: replication proven useless in R8)
    const int* __restrict__ node_idx, const int* __restrict__ edge_idx,
    int* __restrict__ ncnt, int* __restrict__ ecnt,
    int* __restrict__ r_n, int* __restrict__ r_e,
    int nnz, int M_, int N_, int histBlocks,
    // se
    const float* __restrict__ traj, const float* __restrict__ W,
    const float* __restrict__ att, const float* __restrict__ hw,
    float* __restrict__ s_e, float2* __restrict__ se_hw)
{
  __shared__ float wv[128];
  int b = blockIdx.x;
  int tid = threadIdx.x;

  if (b < histBlocks) {
    int t = b * 256 + tid;
    int j = t * 2;
    if (j >= nnz) return;
    if (j + 2 <= nnz) {
      int2 e = *(const int2*)&edge_idx[j];
      int2 n = *(const int2*)&node_idx[j];
      int a0 = atomicAdd(&ecnt[e.x], 1);
      int a1 = atomicAdd(&ecnt[e.y], 1);
      int b0 = atomicAdd(&ncnt[n.x], 1);
      int b1 = atomicAdd(&ncnt[n.y], 1);
      *(int2*)&r_e[j] = make_int2(a0, a1);
      *(int2*)&r_n[j] = make_int2(b0, b1);
    } else {
      r_e[j] = atomicAdd(&ecnt[edge_idx[j]], 1);
      r_n[j] = atomicAdd(&ncnt[node_idx[j]], 1);
    }
    return;
  }

  // ---- se branch ----
  if (tid < 128) {
    const float* wr = W + (size_t)tid * 128;
    float acc = 0.0f;
#pragma unroll 4
    for (int k = 0; k < 128; ++k) acc = fmaf(wr[k], att[DIM + k], acc);
    wv[tid] = acc;
  }
  __syncthreads();
  int e = (b - histBlocks) * 4 + (tid >> 6);
  int lane = tid & 63;
  if (e >= M_) return;
  const float* row = traj + (size_t)e * DIM;
  float v = row[lane] * wv[lane] + row[lane + 64] * wv[lane + 64];
#pragma unroll
  for (int d = 32; d > 0; d >>= 1) v += __shfl_down(v, d, 64);
  if (lane == 0) {
    s_e[e] = v;
    float2 g; g.x = v; g.y = hw[e];
    se_hw[e] = g;
  }
}

// ---------------------------------------------------------------------------
// MFMA GEMM (fp16): Y_h = X_h @ W (Wswz pre-swizzled), fused s_n epilogue.
// ---------------------------------------------------------------------------
__global__ __launch_bounds__(256) void gemm_mfma_kernel(
    const ushort* __restrict__ Xb, const ushort* __restrict__ Wswz,
    const float* __restrict__ att, ushort* __restrict__ Yb,
    float* __restrict__ s_n, int rowsN)
{
  __shared__ ushort st[64 * 128];
  int tid = threadIdx.x;
  int w = tid >> 6, lane = tid & 63;
  int q = lane >> 4, c = lane & 15;
  int r0b = blockIdx.x * 64;
  int r0 = r0b + w * 16;
  float4v acc[8];
#pragma unroll
  for (int nt = 0; nt < 8; ++nt) acc[nt] = (float4v){0.f, 0.f, 0.f, 0.f};
  const ushort* arow = Xb + (size_t)(r0 + c) * DIM + q * 8;
#pragma unroll
  for (int kt = 0; kt < 4; ++kt) {
    half8v a = *(const half8v*)(arow + kt * 32);
#pragma unroll
    for (int nt = 0; nt < 8; ++nt) {
      half8v b = *(const half8v*)(Wswz + ((((kt << 3) + nt) << 9) + (lane << 3)));
      acc[nt] = __builtin_amdgcn_mfma_f32_16x16x32_f16(a, b, acc[nt], 0, 0, 0);
    }
  }
  float av[8];
#pragma unroll
  for (int nt = 0; nt < 8; ++nt) av[nt] = att[nt * 16 + c];
  float p0 = 0, p1 = 0, p2 = 0, p3 = 0;
#pragma unroll
  for (int nt = 0; nt < 8; ++nt) {
    p0 = fmaf(acc[nt][0], av[nt], p0);
    p1 = fmaf(acc[nt][1], av[nt], p1);
    p2 = fmaf(acc[nt][2], av[nt], p2);
    p3 = fmaf(acc[nt][3], av[nt], p3);
  }
#pragma unroll
  for (int m = 8; m >= 1; m >>= 1) {
    p0 += __shfl_xor(p0, m, 64);
    p1 += __shfl_xor(p1, m, 64);
    p2 += __shfl_xor(p2, m, 64);
    p3 += __shfl_xor(p3, m, 64);
  }
  if (c == 0) {
    int rb = r0 + q * 4;
    if (rb + 0 < rowsN) s_n[rb + 0] = p0;
    if (rb + 1 < rowsN) s_n[rb + 1] = p1;
    if (rb + 2 < rowsN) s_n[rb + 2] = p2;
    if (rb + 3 < rowsN) s_n[rb + 3] = p3;
  }
  ushort* sw = st + w * 2048;
#pragma unroll
  for (int nt = 0; nt < 8; ++nt) {
    sw[(q * 4 + 0) * 128 + nt * 16 + c] = f2h_us(acc[nt][0]);
    sw[(q * 4 + 1) * 128 + nt * 16 + c] = f2h_us(acc[nt][1]);
    sw[(q * 4 + 2) * 128 + nt * 16 + c] = f2h_us(acc[nt][2]);
    sw[(q * 4 + 3) * 128 + nt * 16 + c] = f2h_us(acc[nt][3]);
  }
  __syncthreads();
#pragma unroll
  for (int it = 0; it < 4; ++it) {
    int idx = tid + it * 256;           // 0..1023 x ushort8
    int row = idx >> 4, seg = idx & 15;
    *(uint4*)(Yb + (size_t)(r0b + row) * DIM + seg * 8) =
        *(const uint4*)&st[row * 128 + seg * 8];
  }
}

// ---------------------------------------------------------------------------
// Two-level exclusive scan (operates directly on single counter arrays)
// ---------------------------------------------------------------------------
__global__ __launch_bounds__(1024) void scan_block_kernel(
    const int* __restrict__ cnt, int* __restrict__ off,
    int* __restrict__ partials, int nbins)
{
  __shared__ int ws[16];
  int tid = threadIdx.x, lane = tid & 63, wid = tid >> 6;
  int base = blockIdx.x * 4096 + tid * 4;
  int x0 = base + 0 < nbins ? cnt[base + 0] : 0;
  int x1 = base + 1 < nbins ? cnt[base + 1] : 0;
  int x2 = base + 2 < nbins ? cnt[base + 2] : 0;
  int x3 = base + 3 < nbins ? cnt[base + 3] : 0;
  int t = x0 + x1 + x2 + x3;
  int v = t;
#pragma unroll
  for (int d = 1; d < 64; d <<= 1) {
    int y = __shfl_up(v, d, 64);
    if (lane >= d) v += y;
  }
  if (lane == 63) ws[wid] = v;
  __syncthreads();
  if (tid < 16) {
    int s = ws[tid];
#pragma unroll
    for (int d = 1; d < 16; d <<= 1) {
      int y = __shfl_up(s, d, 16);
      if (tid >= d) s += y;
    }
    ws[tid] = s;
  }
  __syncthreads();
  int pre = (wid > 0 ? ws[wid - 1] : 0) + (v - t);
  if (base + 0 < nbins) off[base + 0] = pre;
  if (base + 1 < nbins) off[base + 1] = pre + x0;
  if (base + 2 < nbins) off[base + 2] = pre + x0 + x1;
  if (base + 3 < nbins) off[base + 3] = pre + x0 + x1 + x2;
  if (tid == 0) partials[blockIdx.x] = ws[15];
}

__global__ __launch_bounds__(64) void scan_partials_kernel(
    int* __restrict__ partials, int nb)
{
  int lane = threadIdx.x;
  int t = lane < nb ? partials[lane] : 0;
  int v = t;
#pragma unroll
  for (int d = 1; d < 64; d <<= 1) {
    int y = __shfl_up(v, d, 64);
    if (lane >= d) v += y;
  }
  if (lane < nb) partials[lane] = v - t;
  if (lane == 63) partials[nb] = v;
}

__global__ void add_off_kernel(int* __restrict__ off,
                               const int* __restrict__ partials,
                               int nbins, int nb)
{
  int i = blockIdx.x * blockDim.x + threadIdx.x;
  if (i < nbins) off[i] += partials[i >> 12];
  if (i == 0) off[nbins] = partials[nb];
}

// ---------------------------------------------------------------------------
// SPLIT atomic-free CSR scatters: pos = off[bin] + global_rank
// ---------------------------------------------------------------------------
__global__ void scatter_edge_kernel(const int* __restrict__ node_idx,
                                    const int* __restrict__ edge_idx,
                                    const int* __restrict__ r_e,
                                    const int* __restrict__ eoff,
                                    int* __restrict__ nd_e, int nnz)
{
  int j = (blockIdx.x * blockDim.x + threadIdx.x) * 4;
  if (j >= nnz) return;
  if (j + 4 <= nnz) {
    int4 e = *(const int4*)&edge_idx[j];
    int4 n = *(const int4*)&node_idx[j];
    int4 re = *(const int4*)&r_e[j];
    nd_e[eoff[e.x] + re.x] = n.x;
    nd_e[eoff[e.y] + re.y] = n.y;
    nd_e[eoff[e.z] + re.z] = n.z;
    nd_e[eoff[e.w] + re.w] = n.w;
  } else {
    for (int k = j; k < nnz; ++k) nd_e[eoff[edge_idx[k]] + r_e[k]] = node_idx[k];
  }
}

__global__ void scatter_node_kernel(const int* __restrict__ node_idx,
                                    const int* __restrict__ edge_idx,
                                    const int* __restrict__ r_n,
                                    const int* __restrict__ noff,
                                    int* __restrict__ eidx_n, int nnz)
{
  int j = (blockIdx.x * blockDim.x + threadIdx.x) * 4;
  if (j >= nnz) return;
  if (j + 4 <= nnz) {
    int4 e = *(const int4*)&edge_idx[j];
    int4 n = *(const int4*)&node_idx[j];
    int4 rn = *(const int4*)&r_n[j];
    eidx_n[noff[n.x] + rn.x] = e.x;
    eidx_n[noff[n.y] + rn.y] = e.y;
    eidx_n[noff[n.z] + rn.z] = e.z;
    eidx_n[noff[n.w] + rn.w] = e.w;
  } else {
    for (int k = j; k < nnz; ++k) eidx_n[noff[node_idx[k]] + r_n[k]] = edge_idx[k];
  }
}

// ---------------------------------------------------------------------------
// Per-node softmax stats + weighted degree
// ---------------------------------------------------------------------------
__global__ void softstat_kernel(const int* __restrict__ noff,
                                const int* __restrict__ eidx_n,
                                const float* __restrict__ s_n,
                                const float2* __restrict__ se_hw,
                                float2* __restrict__ ns2,
                                float* __restrict__ Dinv, int N_)
{
  int n = blockIdx.x * blockDim.x + threadIdx.x;
  if (n >= N_) return;
  int s = noff[n], e1 = noff[n + 1];
  float sn = s_n[n];
  float m = -INFINITY, den = 0.0f, d = 0.0f;
  int t = s;
  for (; t + 4 <= e1; t += 4) {
    int i0 = eidx_n[t], i1 = eidx_n[t + 1], i2 = eidx_n[t + 2], i3 = eidx_n[t + 3];
    float2 g0 = se_hw[i0], g1 = se_hw[i1], g2 = se_hw[i2], g3 = se_hw[i3];
    float l0 = lrelu(sn + g0.x), l1 = lrelu(sn + g1.x);
    float l2 = lrelu(sn + g2.x), l3 = lrelu(sn + g3.x);
    float mm = fmaxf(fmaxf(fmaxf(l0, l1), fmaxf(l2, l3)), m);
    den = den * __expf(m - mm) + __expf(l0 - mm) + __expf(l1 - mm)
        + __expf(l2 - mm) + __expf(l3 - mm);
    m = mm;
    d += g0.y + g1.y + g2.y + g3.y;
  }
  for (; t < e1; ++t) {
    float2 g = se_hw[eidx_n[t]];
    float l = lrelu(sn + g.x);
    float mm = fmaxf(l, m);
    den = den * __expf(m - mm) + __expf(l - mm);
    m = mm;
    d += g.y;
  }
  if (s == e1) m = 0.0f;
  float2 r;
  r.x = sn;
  r.y = m + __logf(den + 1e-16f);
  ns2[n] = r;
  Dinv[n] = d > 0.0f ? 1.0f / d : 0.0f;
}

// ---------------------------------------------------------------------------
// msg1 WIDE: wave per edge; lane = (row-group r = lane>>4, col-group c = lane&15).
// One uint4 gather instruction covers 4 incidence rows (64 lanes x 16B = 1KB).
// ---------------------------------------------------------------------------
__global__ __launch_bounds__(256) void msg1_kernel(
    const int* __restrict__ eoff, const int* __restrict__ nd_e,
    const float2* __restrict__ ns2, const float* __restrict__ s_e,
    const uint4* __restrict__ xt16, uint4* __restrict__ eo16, int M_)
{
  int e = blockIdx.x * 4 + (threadIdx.x >> 6);
  int lane = threadIdx.x & 63;
  int r = lane >> 4, c = lane & 15;
  if (e >= M_) return;
  int s = eoff[e], t1 = eoff[e + 1];
  int len = t1 - s;
  float binv = len > 0 ? 1.0f / (float)len : 0.0f;
  float se = s_e[e];
  float acc[8];
#pragma unroll
  for (int j = 0; j < 8; ++j) acc[j] = 0.0f;
  for (int t = s; t < t1; t += 8) {
#pragma unroll
    for (int h = 0; h < 2; ++h) {
      int tb = t + h * 4;
      if (tb < t1) {
        int ti = tb + r;
        int tc = ti < t1 ? ti : t1 - 1;
        float valid = ti < t1 ? 1.0f : 0.0f;
        int nd = nd_e[tc];
        float2 q = ns2[nd];
        float coef = valid * __expf(lrelu(q.x + se) - q.y);
        uint4 g = xt16[(size_t)nd * 16 + c];
        float2 f0 = h2f2(g.x), f1 = h2f2(g.y), f2 = h2f2(g.z), f3 = h2f2(g.w);
        acc[0] = fmaf(coef, f0.x, acc[0]);
        acc[1] = fmaf(coef, f0.y, acc[1]);
        acc[2] = fmaf(coef, f1.x, acc[2]);
        acc[3] = fmaf(coef, f1.y, acc[3]);
        acc[4] = fmaf(coef, f2.x, acc[4]);
        acc[5] = fmaf(coef, f2.y, acc[5]);
        acc[6] = fmaf(coef, f3.x, acc[6]);
        acc[7] = fmaf(coef, f3.y, acc[7]);
      }
    }
  }
#pragma unroll
  for (int j = 0; j < 8; ++j) {
    acc[j] += __shfl_xor(acc[j], 16, 64);
    acc[j] += __shfl_xor(acc[j], 32, 64);
  }
  if (r == 0) {
    uint4 o;
    o.x = packh2(acc[0] * binv, acc[1] * binv);
    o.y = packh2(acc[2] * binv, acc[3] * binv);
    o.z = packh2(acc[4] * binv, acc[5] * binv);
    o.w = packh2(acc[6] * binv, acc[7] * binv);
    eo16[(size_t)e * 16 + c] = o;
  }
}

// ---------------------------------------------------------------------------
// msg2 WIDE: fp16 residual chain (cin always fp16) + lazy stack-sum epilogue.
//  mode 0/1: out = cur_h (fp16)
//  mode 2:   dout = 0.25*(h(x1h) + h(x2h) + cin + cx)
// ---------------------------------------------------------------------------
__global__ __launch_bounds__(256) void msg2_kernel(
    const int* __restrict__ noff, const int* __restrict__ eidx_n,
    const float2* __restrict__ ns2, const float* __restrict__ Dinv,
    const float* __restrict__ s_e, const uint4* __restrict__ eo16,
    const float* __restrict__ bias,
    const uint4* __restrict__ cin_h16,
    const uint4* __restrict__ x1h16, const uint4* __restrict__ x2h16,
    uint4* __restrict__ couth16, float* __restrict__ dout,
    int mode, int N_)
{
  int n = blockIdx.x * 4 + (threadIdx.x >> 6);
  int lane = threadIdx.x & 63;
  int r = lane >> 4, c = lane & 15;
  if (n >= N_) return;
  int s = noff[n], t1 = noff[n + 1];
  float2 nsv = ns2[n];
  float sn = nsv.x, lz = nsv.y;
  float acc[8];
#pragma unroll
  for (int j = 0; j < 8; ++j) acc[j] = 0.0f;
  for (int t = s; t < t1; t += 8) {
#pragma unroll
    for (int h = 0; h < 2; ++h) {
      int tb = t + h * 4;
      if (tb < t1) {
        int ti = tb + r;
        int tc = ti < t1 ? ti : t1 - 1;
        float valid = ti < t1 ? 1.0f : 0.0f;
        int ed = eidx_n[tc];
        float xs = s_e[ed];
        float coef = valid * __expf(lrelu(sn + xs) - lz);
        uint4 g = eo16[(size_t)ed * 16 + c];
        float2 f0 = h2f2(g.x), f1 = h2f2(g.y), f2 = h2f2(g.z), f3 = h2f2(g.w);
        acc[0] = fmaf(coef, f0.x, acc[0]);
        acc[1] = fmaf(coef, f0.y, acc[1]);
        acc[2] = fmaf(coef, f1.x, acc[2]);
        acc[3] = fmaf(coef, f1.y, acc[3]);
        acc[4] = fmaf(coef, f2.x, acc[4]);
        acc[5] = fmaf(coef, f2.y, acc[5]);
        acc[6] = fmaf(coef, f3.x, acc[6]);
        acc[7] = fmaf(coef, f3.y, acc[7]);
      }
    }
  }
#pragma unroll
  for (int j = 0; j < 8; ++j) {
    acc[j] += __shfl_xor(acc[j], 16, 64);
    acc[j] += __shfl_xor(acc[j], 32, 64);
  }
  if (r != 0) return;
  float sc = Dinv[n];
  uint4 ch = cin_h16[(size_t)n * 16 + c];
  float2 p0 = h2f2(ch.x), p1 = h2f2(ch.y), p2 = h2f2(ch.z), p3 = h2f2(ch.w);
  float cin[8] = {p0.x, p0.y, p1.x, p1.y, p2.x, p2.y, p3.x, p3.y};
  const float4* bf = (const float4*)bias;
  float4 ba = bf[c * 2], bb = bf[c * 2 + 1];
  float bs[8] = {ba.x, ba.y, ba.z, ba.w, bb.x, bb.y, bb.z, bb.w};
  float cx[8];
#pragma unroll
  for (int j = 0; j < 8; ++j) cx[j] = cin[j] + acc[j] * sc + bs[j];
  if (mode == 2) {
    uint4 x1 = x1h16[(size_t)n * 16 + c];
    float2 z0 = h2f2(x1.x), z1 = h2f2(x1.y), z2 = h2f2(x1.z), z3 = h2f2(x1.w);
    float x1v[8] = {z0.x, z0.y, z1.x, z1.y, z2.x, z2.y, z3.x, z3.y};
    uint4 x2 = x2h16[(size_t)n * 16 + c];
    float2 y0 = h2f2(x2.x), y1 = h2f2(x2.y), y2 = h2f2(x2.z), y3 = h2f2(x2.w);
    float x2v[8] = {y0.x, y0.y, y1.x, y1.y, y2.x, y2.y, y3.x, y3.y};
    float4 o0, o1;
    o0.x = (x1v[0] + x2v[0] + cin[0] + cx[0]) * 0.25f;
    o0.y = (x1v[1] + x2v[1] + cin[1] + cx[1]) * 0.25f;
    o0.z = (x1v[2] + x2v[2] + cin[2] + cx[2]) * 0.25f;
    o0.w = (x1v[3] + x2v[3] + cin[3] + cx[3]) * 0.25f;
    o1.x = (x1v[4] + x2v[4] + cin[4] + cx[4]) * 0.25f;
    o1.y = (x1v[5] + x2v[5] + cin[5] + cx[5]) * 0.25f;
    o1.z = (x1v[6] + x2v[6] + cin[6] + cx[6]) * 0.25f;
    o1.w = (x1v[7] + x2v[7] + cin[7] + cx[7]) * 0.25f;
    float4* dp = (float4*)(dout + (size_t)n * DIM);
    dp[c * 2] = o0;
    dp[c * 2 + 1] = o1;
  } else {
    uint4 o;
    o.x = packh2(cx[0], cx[1]);
    o.y = packh2(cx[2], cx[3]);
    o.z = packh2(cx[4], cx[5]);
    o.w = packh2(cx[6], cx[7]);
    couth16[(size_t)n * 16 + c] = o;
  }
}

// ---------------------------------------------------------------------------
static inline int cdiv(int a, int b) { return (a + b - 1) / b; }

extern "C" void kernel_launch(void* const* d_in, const int* in_sizes, int n_in,
                              void* d_out, int out_size, void* d_ws, size_t ws_size,
                              hipStream_t stream)
{
  const float* pois = (const float*)d_in[0];
  const float* traj = (const float*)d_in[1];
  const float* hw   = (const float*)d_in[2];
  const int* node_idx = (const int*)d_in[3];
  const int* edge_idx = (const int*)d_in[4];
  const float* W    = (const float*)d_in[5];
  const float* att  = (const float*)d_in[6];
  const float* bias = (const float*)d_in[7];
  float* dout = (float*)d_out;

  const int N   = in_sizes[0] / DIM;
  const int M   = in_sizes[2];
  const int NNZ = in_sizes[3];
  const int NP  = (N + 63) & ~63;   // row-padded for 64-row MFMA tiles

  char* p = (char*)d_ws;
  auto alloc = [&](size_t bytes) -> void* {
    void* r = (void*)p;
    p += (bytes + 255) & ~(size_t)255;
    return r;
  };
  ushort* xt_h    = (ushort*)alloc((size_t)NP * DIM * 2);
  ushort* pois_h  = (ushort*)alloc((size_t)NP * DIM * 2);
  uint*   cura_h  = (uint*)alloc((size_t)NP * 64 * 4);   // cur1 fp16
  uint*   curb_h  = (uint*)alloc((size_t)NP * 64 * 4);   // cur2 fp16
  ushort* W_swz   = (ushort*)alloc(16384 * 2);
  uint*   eo_h  = (uint*)alloc((size_t)M * (DIM / 2) * 4);
  float2* ns2   = (float2*)alloc((size_t)N * 8);
  float*  s_e  = (float*)alloc((size_t)M * 4);
  float2* se_hw = (float2*)alloc((size_t)M * 8);
  float*  s_n  = (float*)alloc((size_t)N * 4);
  float*  Dinv = (float*)alloc((size_t)N * 4);
  int* ecnt = (int*)alloc((size_t)M * 4);
  int* ncnt = (int*)alloc((size_t)N * 4);
  int* eoff = (int*)alloc((size_t)(M + 1) * 4);
  int* noff = (int*)alloc((size_t)(N + 1) * 4);
  int* r_e  = (int*)alloc((size_t)NNZ * 4);
  int* r_n  = (int*)alloc((size_t)NNZ * 4);
  int* nd_e   = (int*)alloc((size_t)NNZ * 4);
  int* eidx_n = (int*)alloc((size_t)NNZ * 4);
  int* part_e = (int*)alloc(65 * 4);
  int* part_n = (int*)alloc(65 * 4);
  (void)ws_size;

  const int nbE = cdiv(M, 4096), nbN = cdiv(N, 4096);
  const int histBlocks = cdiv(NNZ, 512);   // 1 pair/thread
  const int seBlocks = cdiv(M, 4);

  // ---- prep: fp16 mirrors + W swizzle + counter zero ----
  hipMemsetAsync(ecnt, 0, (size_t)M * 4, stream);
  hipMemsetAsync(ncnt, 0, (size_t)N * 4, stream);
  wswz_kernel<<<64, 256, 0, stream>>>(W, W_swz);
  poish_kernel<<<cdiv(NP * 16, 256), 256, 0, stream>>>(pois, (uint4*)pois_h, N, NP);

  // ---- fused hist+se (small footprint: hist keeps full occupancy) ----
  hist_se_fused_kernel<<<histBlocks + seBlocks, 256, 0, stream>>>(
      node_idx, edge_idx, ncnt, ecnt, r_n, r_e, NNZ, M, N, histBlocks,
      traj, W, att, hw, s_e, se_hw);

  // ---- CSR finalize (single counters: rank is already global) ----
  scan_block_kernel<<<nbE, 1024, 0, stream>>>(ecnt, eoff, part_e, M);
  scan_block_kernel<<<nbN, 1024, 0, stream>>>(ncnt, noff, part_n, N);
  scan_partials_kernel<<<1, 64, 0, stream>>>(part_e, nbE);
  scan_partials_kernel<<<1, 64, 0, stream>>>(part_n, nbN);
  add_off_kernel<<<cdiv(M, 256), 256, 0, stream>>>(eoff, part_e, M, nbE);
  add_off_kernel<<<cdiv(N, 256), 256, 0, stream>>>(noff, part_n, N, nbN);
  scatter_edge_kernel<<<cdiv(NNZ, 1024), 256, 0, stream>>>(node_idx, edge_idx, r_e, eoff, nd_e, NNZ);
  scatter_node_kernel<<<cdiv(NNZ, 1024), 256, 0, stream>>>(node_idx, edge_idx, r_n, noff, eidx_n, NNZ);

  // ---- layers ----
  // L0: gemm(pois_h); msg2: cin=pois_h -> cura_h
  // L1: gemm(cura_h); msg2: cin=cura_h -> curb_h
  // L2: gemm(curb_h); msg2 mode2: cin=curb_h, x1=pois_h, x2=cura_h -> dout
  for (int layer = 0; layer < 3; ++layer) {
    const ushort* gin = (layer == 0) ? pois_h
                       : (layer == 1) ? (const ushort*)cura_h
                                      : (const ushort*)curb_h;
    gemm_mfma_kernel<<<NP / 64, 256, 0, stream>>>(gin, W_swz, att, xt_h, s_n, N);
    softstat_kernel<<<cdiv(N, 256), 256, 0, stream>>>(noff, eidx_n, s_n, se_hw, ns2, Dinv, N);
    msg1_kernel<<<cdiv(M, 4), 256, 0, stream>>>(eoff, nd_e, ns2, s_e,
                                                (const uint4*)xt_h, (uint4*)eo_h, M);
    const uint* cin_h = (layer == 0) ? (const uint*)pois_h
                       : (layer == 1) ? cura_h : curb_h;
    uint* couth = (layer == 0) ? cura_h : curb_h;
    msg2_kernel<<<cdiv(N, 4), 256, 0, stream>>>(noff, eidx_n, ns2, Dinv, s_e,
                                                (const uint4*)eo_h, bias,
                                                (const uint4*)cin_h,
                                                (const uint4*)pois_h,
                                                (const uint4*)cura_h,
                                                (uint4*)couth, dout, layer, N);
  }
}